// Round 9
// baseline (515.939 us; speedup 1.0000x reference)
//
#include <hip/hip_runtime.h>
#include <cstdint>
#include <cstddef>

#define TSTEPS 512
#define INP    24
#define HID    128
#define BB     4      // batch elems per block; 256 blocks (1/CU)
#define NKT    5      // K = 128 h + 24 x + 8 pad = 160 = 5 tiles of 32
#define VSTR   168    // v[] column stride in fp16 elems: [h 0..127 | x 128..151 | pad]

typedef __attribute__((ext_vector_type(8))) _Float16 half8;   // 8 x fp16 (4 VGPRs)
typedef __attribute__((ext_vector_type(4))) float f32x4;

__device__ __forceinline__ float rcp_f(float v) { return __builtin_amdgcn_rcpf(v); }
// fast sigmoid: exp + rcp (no precise-div sequence); ~1ulp rcp fine at fp16 state
__device__ __forceinline__ float sigm_f(float v) {
    return rcp_f(1.0f + __expf(-v));
}
// branchless tanh: 1 - 2/(1+e^{2v}); saturates correctly at +-inf, no fabs/select
__device__ __forceinline__ float tanh_f(float v) {
    return 1.0f - 2.0f * rcp_f(1.0f + __expf(2.0f * v));
}
__device__ __forceinline__ unsigned pack2h(float a, float b) {
    union { _Float16 h[2]; unsigned u; } z;
    z.h[0] = (_Float16)a; z.h[1] = (_Float16)b;   // v_cvt_f16_f32, RTN
    return z.u;
}

// ROUND LESSONS ENCODED:
//  R1: VGPR-cap betrayal -> scratch spill shows as WRITE_SIZE GBs. Watch it.
//  R2: runtime-varying index into per-thread arrays demotes to memory.
//  R3: fp32 VALU ~3x too slow; use MFMA.
//  R4/R5: total time == per-block time; batch-per-block is irrelevant to
//       total as long as all blocks run concurrently. MINIMIZE BLOCK WALL.
//  R6: mfma ~19.4 cyc/SIMD (4.85 is per-CU). Phases sum.
//  R7: (revised this round) most of the 4.6e7 conflict counter is the
//       full-wave b128 1024B/op cost (8-cyc floor at 128B/cyc), not real
//       conflicts. 12 of 16 cols read were zeros.
//  R8: LDS pipe is PER-CU; shared by 4 SIMDs.
//  R9: single-pass fp16 weights/state; ranges safe, absmax ~2^-11.
//  R10: wave-local redistribution -> ONE barrier/ts. 619->542us.
//  R11/R12: occupancy attrs clamp VGPR 96->64 -> spill -> 777us.
//  R13: no attr: no spill but HW still 1 block/CU. Don't depend on
//       residency rules.
//  R14: 2x mfma work/wave: phases SUM within a wave (serial chain).
//  R15: cell update on 16 lanes x 4: VALU issue is per-wave regardless of
//       exec mask -> 4x consumer stream. Elementwise stays on 64 lanes.
//  R16: bias->mfma C-init + rcp sigm/tanh + pre-barrier x-tile mfma:
//       542->453us. Chain model confirmed (phases move the wall 1:1).
//       Budget now: mfma 776/SIMD, VALU ~510, LDS ~660-800/CU, barrier.
//  R17 (this): MASK B-FRAG READS TO THE 4 REAL COLUMNS. bh=0 unless
//      ncol<4 (exec-masked ds_read: 256B/op, ~2-3cyc vs 12). D cols 4-15
//      = bias+0 garbage, never read (producer masks). v_s shrunk to 4
//      cols (~12KB LDS). Predict 380-405us, conflicts ~2e7, MfmaUtil
//      40-44. Falsifier: conflicts drop but dur <5% -> latency/barrier
//      bound -> phase-shifted cohorts next.
//
// Per ts: gates[512 x 4real] = W[512 x 160] @ v[160 x 4], cols 0..3 real.
// mfma_f32_16x16x32_f16:
//   A-frag: lane holds A[m=lane&15][k=quad*8+j]
//   B-frag: lane holds B[k=quad*8+j][n=lane&15]
//   C/D:    col=lane&15, row=quad*4+reg
__global__ __launch_bounds__(512)
void lstm_fused(
    const float* __restrict__ x,      // [B, T, 24]
    const float* __restrict__ addin,  // [B, 2]
    const float* __restrict__ W_ih,   // [512, 24]
    const float* __restrict__ W_hh,   // [512, 128]
    const float* __restrict__ b_ih,   // [512]
    const float* __restrict__ b_hh,   // [512]
    const float* __restrict__ W1,     // [64, 130]
    const float* __restrict__ b1,     // [64]
    const float* __restrict__ W2,     // [3, 64]
    const float* __restrict__ b2,     // [3]
    float* __restrict__ out)          // [B, 3]
{
    __shared__ _Float16 v_s[2][BB * VSTR];   // [buf][col<4][k']; k'<128 h, 128..151 x
    __shared__ float part_s[8][256];         // per-wave slice: [g*64 + b*16 + u]
    __shared__ float z_s[BB][64];

    const int t    = threadIdx.x;      // 512 threads = 8 waves
    const int lane = t & 63;
    const int wv   = t >> 6;           // 0..7: owns unit rows wv*16..+15 (x4 gates)
    const int ncol = lane & 15;        // batch col (0..3 real)
    const int quad = lane >> 4;
    const int b0   = blockIdx.x * BB;
    const bool realc = (ncol < BB);

    // ---- persistent A-fragments (fp16), k' layout: [W_hh | W_ih | 0] ----
    half8 A_w[4][NKT];
    #pragma unroll
    for (int g = 0; g < 4; ++g) {
        const int row = g * HID + wv * 16 + ncol;
        #pragma unroll
        for (int kt = 0; kt < NKT; ++kt) {
            half8 frag;
            #pragma unroll
            for (int j = 0; j < 8; ++j) {
                const int k = kt * 32 + quad * 8 + j;
                float w = 0.0f;
                if (k < HID)            w = W_hh[row * HID + k];
                else if (k < HID + INP) w = W_ih[row * INP + (k - HID)];
                frag[j] = (_Float16)w;
            }
            A_w[g][kt] = frag;
        }
    }

    // bias as mfma C-init: biasv[g][r] for row quad*4+r (same for all cols)
    f32x4 biasv[4];
    #pragma unroll
    for (int g = 0; g < 4; ++g) {
        #pragma unroll
        for (int r = 0; r < 4; ++r) {
            const int u = wv * 16 + quad * 4 + r;
            biasv[g][r] = b_ih[g * HID + u] + b_hh[g * HID + u];
        }
    }

    // consumer role: lane -> (batch cb, unit cu) of THIS wave's 16 units
    const int cb = lane & 3;           // batch 0..3
    const int cu = lane >> 2;          // unit-local 0..15
    const int uj = wv * 16 + cu;       // absolute unit
    float c_reg = 0.0f;
    float* const pw = &part_s[wv][0];
    const int ci = cb * 16 + cu;

    // x-staging role: t<48 handles batch xb, k-pair kk*2
    const int xb = t / 12;
    const int kk = t - xb * 12;
    const size_t xrow = (size_t)(b0 + xb) * TSTEPS;

    // ---- init: zero both buffers; stage x(0)->buf0, x(1)->buf1; xq=x(2) ----
    for (int i = t; i < BB * VSTR; i += 512) {
        v_s[0][i] = (_Float16)0.0f; v_s[1][i] = (_Float16)0.0f;
    }
    __syncthreads();
    if (t < 48) {
        const float2 x0 = *(const float2*)(x + (xrow + 0) * INP + kk * 2);
        const float2 x1 = *(const float2*)(x + (xrow + 1) * INP + kk * 2);
        *(unsigned*)&v_s[0][xb * VSTR + HID + kk * 2] = pack2h(x0.x, x0.y);
        *(unsigned*)&v_s[1][xb * VSTR + HID + kk * 2] = pack2h(x1.x, x1.y);
    }
    float2 xq = {0.f, 0.f};
    if (t < 48) {
        xq = *(const float2*)(x + (xrow + 2) * INP + kk * 2);
    }
    __syncthreads();

    // prologue pre-step for ts=0: x-tile (kt4) from buf0, C-init = bias
    f32x4 aci, acf, acg, aco;
    {
        half8 bx = {};
        if (realc) bx = *(const half8*)(&v_s[0][0] + ncol * VSTR + HID + quad * 8);
        aci = __builtin_amdgcn_mfma_f32_16x16x32_f16(A_w[0][4], bx, biasv[0], 0, 0, 0);
        acf = __builtin_amdgcn_mfma_f32_16x16x32_f16(A_w[1][4], bx, biasv[1], 0, 0, 0);
        acg = __builtin_amdgcn_mfma_f32_16x16x32_f16(A_w[2][4], bx, biasv[2], 0, 0, 0);
        aco = __builtin_amdgcn_mfma_f32_16x16x32_f16(A_w[3][4], bx, biasv[3], 0, 0, 0);
    }
    __syncthreads();   // protect buf0 x-region before iter0 overwrites it

    // ---- recurrence: ONE barrier per ts ----
    #pragma unroll 2
    for (int ts = 0; ts < TSTEPS; ++ts) {
        const int pb = ts & 1, nb = pb ^ 1;

        // top: stage x(ts+2) into pb (its old x was consumed pre-barrier
        // last iter); issue load of x(ts+3)
        float2 xn = {0.f, 0.f};
        if (t < 48) {
            const int tsn = (ts + 3 < TSTEPS) ? ts + 3 : TSTEPS - 1;
            xn = *(const float2*)(x + (xrow + tsn) * INP + kk * 2);
            *(unsigned*)&v_s[pb][xb * VSTR + HID + kk * 2] = pack2h(xq.x, xq.y);
        }

        // MFMA phase: h-tiles kt0..3; acc starts at carried (bias + x-tile).
        // B-frag reads exec-masked to the 4 real cols (256B/op, not 1024B).
        const _Float16* vh = v_s[pb];
        f32x4 ai = aci, af = acf, ag = acg, ao = aco;
        #pragma unroll
        for (int kt = 0; kt < 4; ++kt) {
            half8 bh = {};
            if (realc) bh = *(const half8*)(vh + ncol * VSTR + kt * 32 + quad * 8);
            ai = __builtin_amdgcn_mfma_f32_16x16x32_f16(A_w[0][kt], bh, ai, 0, 0, 0);
            af = __builtin_amdgcn_mfma_f32_16x16x32_f16(A_w[1][kt], bh, af, 0, 0, 0);
            ag = __builtin_amdgcn_mfma_f32_16x16x32_f16(A_w[2][kt], bh, ag, 0, 0, 0);
            ao = __builtin_amdgcn_mfma_f32_16x16x32_f16(A_w[3][kt], bh, ao, 0, 0, 0);
        }

        // producer: publish bias-included pre-acts into this wave's slice
        if (realc) {
            float* gp = pw + ncol * 16 + quad * 4;
            *(f32x4*)(gp + 0 * 64) = ai;
            *(f32x4*)(gp + 1 * 64) = af;
            *(f32x4*)(gp + 2 * 64) = ag;
            *(f32x4*)(gp + 3 * 64) = ao;
        }

        // consumer: all 64 lanes, one cell each (same-wave DS + lgkmcnt)
        {
            const float gi = sigm_f(pw[0 * 64 + ci]);
            const float gf = sigm_f(pw[1 * 64 + ci]);
            const float gg = tanh_f(pw[2 * 64 + ci]);
            const float go = sigm_f(pw[3 * 64 + ci]);
            c_reg = gf * c_reg + gi * gg;
            const float h = go * tanh_f(c_reg);
            v_s[nb][cb * VSTR + uj] = (_Float16)h;
        }

        // pre-barrier x-tile mfma for ts+1 (independent of consumer chain;
        // overlaps it on the mfma pipe). x(ts+1) is in nb since last epoch.
        {
            half8 bx = {};
            if (realc) bx = *(const half8*)(&v_s[nb][0] + ncol * VSTR + HID + quad * 8);
            aci = __builtin_amdgcn_mfma_f32_16x16x32_f16(A_w[0][4], bx, biasv[0], 0, 0, 0);
            acf = __builtin_amdgcn_mfma_f32_16x16x32_f16(A_w[1][4], bx, biasv[1], 0, 0, 0);
            acg = __builtin_amdgcn_mfma_f32_16x16x32_f16(A_w[2][4], bx, biasv[2], 0, 0, 0);
            aco = __builtin_amdgcn_mfma_f32_16x16x32_f16(A_w[3][4], bx, biasv[3], 0, 0, 0);
        }

        // roll x queue
        if (t < 48) xq = xn;

        // single cross-wave hazard: h(ts) + x(ts+2) visible next epoch
        __syncthreads();
    }

    // ---- FC head: final h is in buffer 0 (ts=511 -> nb=0), offset 0..127 ----
    if (t < 64 * BB) {
        const int b = t >> 6, u = t & 63;
        const float* w = W1 + u * 130;
        float a = b1[u];
        #pragma unroll 16
        for (int k = 0; k < HID; ++k) {
            const float hv = (float)v_s[0][b * VSTR + k];
            a += fmaxf(hv, 0.0f) * w[k];
        }
        const float a0 = addin[(size_t)(b0 + b) * 2 + 0];
        const float a1 = addin[(size_t)(b0 + b) * 2 + 1];
        a += fmaxf(a0, 0.0f) * w[128] + fmaxf(a1, 0.0f) * w[129];
        z_s[b][u] = fmaxf(a, 0.0f);
    }
    __syncthreads();
    if (t < 3 * BB) {
        const int b = t / 3, o = t - 3 * b;
        const float* w = W2 + o * 64;
        float a = b2[o];
        #pragma unroll
        for (int k = 0; k < 64; ++k)
            a += z_s[b][k] * w[k];
        out[(size_t)(b0 + b) * 3 + o] = a;
    }
}

extern "C" void kernel_launch(void* const* d_in, const int* in_sizes, int n_in,
                              void* d_out, int out_size, void* d_ws, size_t ws_size,
                              hipStream_t stream) {
    const float* x     = (const float*)d_in[0];
    const float* addin = (const float*)d_in[1];
    const float* W_ih  = (const float*)d_in[2];
    const float* W_hh  = (const float*)d_in[3];
    const float* b_ih  = (const float*)d_in[4];
    const float* b_hh  = (const float*)d_in[5];
    const float* W1    = (const float*)d_in[6];
    const float* b1    = (const float*)d_in[7];
    const float* W2    = (const float*)d_in[8];
    const float* b2    = (const float*)d_in[9];
    float* outp        = (float*)d_out;

    const int B = in_sizes[0] / (TSTEPS * INP);   // 1024
    const int grid = B / BB;                      // 256 blocks (1 per CU)

    lstm_fused<<<grid, 512, 0, stream>>>(x, addin, W_ih, W_hh, b_ih, b_hh,
                                         W1, b1, W2, b2, outp);
}

// Round 10
// 403.286 us; speedup vs baseline: 1.2793x; 1.2793x over previous
//
#include <hip/hip_runtime.h>
#include <cstdint>
#include <cstddef>

#define TSTEPS 512
#define INP    24
#define HID    128
#define BB     4      // batch elems per block; 256 blocks (1/CU)
#define NKT    5      // K = 128 h + 24 x + 8 pad = 160 = 5 tiles of 32
#define VSTR   168    // v[] column stride in fp16 elems: [h 0..127 | x 128..151 | pad]

typedef __attribute__((ext_vector_type(8))) _Float16 half8;   // 8 x fp16 (4 VGPRs)
typedef __attribute__((ext_vector_type(4))) float f32x4;

__device__ __forceinline__ float rcp_f(float v) { return __builtin_amdgcn_rcpf(v); }
// fast sigmoid: exp + rcp (no precise-div sequence); ~1ulp rcp fine at fp16 state
__device__ __forceinline__ float sigm_f(float v) {
    return rcp_f(1.0f + __expf(-v));
}
// branchless tanh: 1 - 2/(1+e^{2v}); saturates correctly at +-inf
__device__ __forceinline__ float tanh_f(float v) {
    return 1.0f - 2.0f * rcp_f(1.0f + __expf(2.0f * v));
}
__device__ __forceinline__ unsigned pack2h(float a, float b) {
    union { _Float16 h[2]; unsigned u; } z;
    z.h[0] = (_Float16)a; z.h[1] = (_Float16)b;   // v_cvt_f16_f32, RTN
    return z.u;
}
// select a[r] with r = 2*rb1 + rb0; compile-time component indices (R2-safe)
__device__ __forceinline__ float sel4(const f32x4 a, bool rb0, bool rb1) {
    const float lo = rb0 ? a[1] : a[0];
    const float hi = rb0 ? a[3] : a[2];
    return rb1 ? hi : lo;
}

// ROUND LESSONS ENCODED:
//  R1: VGPR-cap betrayal -> scratch spill shows as WRITE_SIZE GBs. Watch it.
//  R2: runtime-varying index into per-thread arrays demotes to memory.
//  R3: fp32 VALU ~3x too slow; use MFMA.
//  R4/R5: total time == per-block time. MINIMIZE BLOCK WALL.
//  R6: mfma ~19.4 cyc/SIMD (4.85 is per-CU). 160 mfma/block/ts is invariant
//       (rows x K fixed); only the wall around it moves.
//  R8: LDS pipe is PER-CU.
//  R9: single-pass fp16 weights/state; ranges safe, absmax ~2^-11.
//  R10: wave-local redistribution -> ONE barrier/ts. 619->542us.
//  R11/R12: occupancy attrs clamp VGPR -> spill. R13: HW won't co-schedule
//       2 blocks/CU regardless. Don't depend on residency rules.
//  R14: phases SUM within a wave (serial chain), extra mfma work not hidden.
//  R15: elementwise on 16 lanes = 4x issue tax. Keep 64 lanes.
//  R16: bias->C-init + rcp sigm/tanh + pre-barrier x-tile: 542->453us.
//  R17: exec-masked B-reads: conflicts 4.6e7->2.5e7 but dur +45us. LDS pipe
//       is NOT the critical path (latency+issue bound); exec-mask dance
//       costs ~200cyc/ts. REVERTED.
//  R18 (this): REPLICA COLUMNS KILL THE REDISTRIBUTION. B-frag read addr
//      clamped to col (ncol&3) -> 4-way LDS broadcast (free, no exec mask)
//      -> D cols 4..15 = exact replicas. Lane (quad,ncol) takes reg
//      r=ncol>>2 -> owns cell (unit quad*4+r, batch ncol&3): bijection
//      over 64 lanes. Redistribution = 12 cndmask (compile-time idx).
//      part_s + producer/consumer phases DELETED (~300 cyc/ts serial).
//      Arithmetic bit-identical -> absmax must stay 0.0004882812.
//      Predict 300-350us, MfmaUtil 45-55, LDS ~4KB, conflicts <=1.5e7.
//
// Per ts: gates[512 x 4] = W[512 x 160] @ v[160 x 4], broadcast to 16 cols.
// mfma_f32_16x16x32_f16:
//   A-frag: lane holds A[m=lane&15][k=quad*8+j]
//   B-frag: lane holds B[k=quad*8+j][n=lane&15]
//   C/D:    col=lane&15, row=quad*4+reg
__global__ __launch_bounds__(512)
void lstm_fused(
    const float* __restrict__ x,      // [B, T, 24]
    const float* __restrict__ addin,  // [B, 2]
    const float* __restrict__ W_ih,   // [512, 24]
    const float* __restrict__ W_hh,   // [512, 128]
    const float* __restrict__ b_ih,   // [512]
    const float* __restrict__ b_hh,   // [512]
    const float* __restrict__ W1,     // [64, 130]
    const float* __restrict__ b1,     // [64]
    const float* __restrict__ W2,     // [3, 64]
    const float* __restrict__ b2,     // [3]
    float* __restrict__ out)          // [B, 3]
{
    __shared__ _Float16 v_s[2][BB * VSTR];   // [buf][col<4][k']; k'<128 h, 128..151 x
    __shared__ float z_s[BB][64];

    const int t    = threadIdx.x;      // 512 threads = 8 waves
    const int lane = t & 63;
    const int wv   = t >> 6;           // 0..7: owns unit rows wv*16..+15 (x4 gates)
    const int ncol = lane & 15;
    const int quad = lane >> 4;
    const int b0   = blockIdx.x * BB;
    const int bsel = ncol & 3;         // broadcast source col = this lane's batch
    const bool rb0 = (ncol >> 2) & 1;  // reg-select bits: r = ncol>>2
    const bool rb1 = (ncol >> 3) & 1;

    // ---- persistent A-fragments (fp16), k' layout: [W_hh | W_ih | 0] ----
    half8 A_w[4][NKT];
    #pragma unroll
    for (int g = 0; g < 4; ++g) {
        const int row = g * HID + wv * 16 + ncol;
        #pragma unroll
        for (int kt = 0; kt < NKT; ++kt) {
            half8 frag;
            #pragma unroll
            for (int j = 0; j < 8; ++j) {
                const int k = kt * 32 + quad * 8 + j;
                float w = 0.0f;
                if (k < HID)            w = W_hh[row * HID + k];
                else if (k < HID + INP) w = W_ih[row * INP + (k - HID)];
                frag[j] = (_Float16)w;
            }
            A_w[g][kt] = frag;
        }
    }

    // bias as mfma C-init: biasv[g][r] for row quad*4+r (same for all cols)
    f32x4 biasv[4];
    #pragma unroll
    for (int g = 0; g < 4; ++g) {
        #pragma unroll
        for (int r = 0; r < 4; ++r) {
            const int u = wv * 16 + quad * 4 + r;
            biasv[g][r] = b_ih[g * HID + u] + b_hh[g * HID + u];
        }
    }

    // cell ownership (bijective over 64 lanes): unit uj, batch bsel
    const int uj = wv * 16 + quad * 4 + (ncol >> 2);
    float c_reg = 0.0f;

    // x-staging role: t<48 handles batch-col sb, k-pair kk*2
    const int sb = t / 12;
    const int kk = t - sb * 12;
    const size_t xrow = (size_t)(b0 + sb) * TSTEPS;

    // ---- init: zero both buffers; stage x(0)->buf0, x(1)->buf1; xq=x(2) ----
    for (int i = t; i < BB * VSTR; i += 512) {
        v_s[0][i] = (_Float16)0.0f; v_s[1][i] = (_Float16)0.0f;
    }
    __syncthreads();
    if (t < 48) {
        const float2 x0 = *(const float2*)(x + (xrow + 0) * INP + kk * 2);
        const float2 x1 = *(const float2*)(x + (xrow + 1) * INP + kk * 2);
        *(unsigned*)&v_s[0][sb * VSTR + HID + kk * 2] = pack2h(x0.x, x0.y);
        *(unsigned*)&v_s[1][sb * VSTR + HID + kk * 2] = pack2h(x1.x, x1.y);
    }
    float2 xq = {0.f, 0.f};
    if (t < 48) {
        xq = *(const float2*)(x + (xrow + 2) * INP + kk * 2);
    }
    __syncthreads();

    // prologue pre-step for ts=0: x-tile (kt4) from buf0, C-init = bias
    f32x4 aci, acf, acg, aco;
    {
        const half8 bx = *(const half8*)(&v_s[0][0] + bsel * VSTR + HID + quad * 8);
        aci = __builtin_amdgcn_mfma_f32_16x16x32_f16(A_w[0][4], bx, biasv[0], 0, 0, 0);
        acf = __builtin_amdgcn_mfma_f32_16x16x32_f16(A_w[1][4], bx, biasv[1], 0, 0, 0);
        acg = __builtin_amdgcn_mfma_f32_16x16x32_f16(A_w[2][4], bx, biasv[2], 0, 0, 0);
        aco = __builtin_amdgcn_mfma_f32_16x16x32_f16(A_w[3][4], bx, biasv[3], 0, 0, 0);
    }
    __syncthreads();   // protect buf0 x-region before iter0 overwrites it

    // ---- recurrence: ONE barrier per ts, NO redistribution ----
    #pragma unroll 2
    for (int ts = 0; ts < TSTEPS; ++ts) {
        const int pb = ts & 1, nb = pb ^ 1;

        // top: stage x(ts+2) into pb (consumed pre-barrier last iter);
        // issue load of x(ts+3)
        float2 xn = {0.f, 0.f};
        if (t < 48) {
            const int tsn = (ts + 3 < TSTEPS) ? ts + 3 : TSTEPS - 1;
            xn = *(const float2*)(x + (xrow + tsn) * INP + kk * 2);
            *(unsigned*)&v_s[pb][sb * VSTR + HID + kk * 2] = pack2h(xq.x, xq.y);
        }

        // read x-frag for ts+1 up front (nb x-region; indep of everything)
        const half8 bx = *(const half8*)(&v_s[nb][0] + bsel * VSTR + HID + quad * 8);

        // MFMA phase: h-tiles kt0..3; acc starts at carried (bias + x-tile).
        // B-frag addr clamped to bsel -> 4-way broadcast, cols 4..15 replicas.
        const _Float16* vh = v_s[pb];
        f32x4 ai = aci, af = acf, ag = acg, ao = aco;
        #pragma unroll
        for (int kt = 0; kt < 4; ++kt) {
            const half8 bh = *(const half8*)(vh + bsel * VSTR + kt * 32 + quad * 8);
            ai = __builtin_amdgcn_mfma_f32_16x16x32_f16(A_w[0][kt], bh, ai, 0, 0, 0);
            af = __builtin_amdgcn_mfma_f32_16x16x32_f16(A_w[1][kt], bh, af, 0, 0, 0);
            ag = __builtin_amdgcn_mfma_f32_16x16x32_f16(A_w[2][kt], bh, ag, 0, 0, 0);
            ao = __builtin_amdgcn_mfma_f32_16x16x32_f16(A_w[3][kt], bh, ao, 0, 0, 0);
        }

        // in-register "redistribution": pick this lane's cell (reg r=ncol>>2)
        const float si = sel4(ai, rb0, rb1);
        const float sf = sel4(af, rb0, rb1);
        const float sg = sel4(ag, rb0, rb1);
        const float so = sel4(ao, rb0, rb1);

        // next-ts x-tile mfma (bx already in regs; independent of the trans
        // chain below -> overlaps it on the mfma pipe)
        aci = __builtin_amdgcn_mfma_f32_16x16x32_f16(A_w[0][4], bx, biasv[0], 0, 0, 0);
        acf = __builtin_amdgcn_mfma_f32_16x16x32_f16(A_w[1][4], bx, biasv[1], 0, 0, 0);
        acg = __builtin_amdgcn_mfma_f32_16x16x32_f16(A_w[2][4], bx, biasv[2], 0, 0, 0);
        aco = __builtin_amdgcn_mfma_f32_16x16x32_f16(A_w[3][4], bx, biasv[3], 0, 0, 0);

        // cell update: ALL 64 lanes, one cell each (no LDS round trip)
        {
            const float gi = sigm_f(si);
            const float gf = sigm_f(sf);
            const float gg = tanh_f(sg);
            const float go = sigm_f(so);
            c_reg = gf * c_reg + gi * gg;
            const float h = go * tanh_f(c_reg);
            v_s[nb][bsel * VSTR + uj] = (_Float16)h;
        }

        // roll x queue
        if (t < 48) xq = xn;

        // single cross-wave hazard: h(ts) + x(ts+2) visible next epoch
        __syncthreads();
    }

    // ---- FC head: final h is in buffer 0 (ts=511 -> nb=0), offset 0..127 ----
    if (t < 64 * BB) {
        const int b = t >> 6, u = t & 63;
        const float* w = W1 + u * 130;
        float a = b1[u];
        #pragma unroll 16
        for (int k = 0; k < HID; ++k) {
            const float hv = (float)v_s[0][b * VSTR + k];
            a += fmaxf(hv, 0.0f) * w[k];
        }
        const float a0 = addin[(size_t)(b0 + b) * 2 + 0];
        const float a1 = addin[(size_t)(b0 + b) * 2 + 1];
        a += fmaxf(a0, 0.0f) * w[128] + fmaxf(a1, 0.0f) * w[129];
        z_s[b][u] = fmaxf(a, 0.0f);
    }
    __syncthreads();
    if (t < 3 * BB) {
        const int b = t / 3, o = t - 3 * b;
        const float* w = W2 + o * 64;
        float a = b2[o];
        #pragma unroll
        for (int k = 0; k < 64; ++k)
            a += z_s[b][k] * w[k];
        out[(size_t)(b0 + b) * 3 + o] = a;
    }
}

extern "C" void kernel_launch(void* const* d_in, const int* in_sizes, int n_in,
                              void* d_out, int out_size, void* d_ws, size_t ws_size,
                              hipStream_t stream) {
    const float* x     = (const float*)d_in[0];
    const float* addin = (const float*)d_in[1];
    const float* W_ih  = (const float*)d_in[2];
    const float* W_hh  = (const float*)d_in[3];
    const float* b_ih  = (const float*)d_in[4];
    const float* b_hh  = (const float*)d_in[5];
    const float* W1    = (const float*)d_in[6];
    const float* b1    = (const float*)d_in[7];
    const float* W2    = (const float*)d_in[8];
    const float* b2    = (const float*)d_in[9];
    float* outp        = (float*)d_out;

    const int B = in_sizes[0] / (TSTEPS * INP);   // 1024
    const int grid = B / BB;                      // 256 blocks (1 per CU)

    lstm_fused<<<grid, 512, 0, stream>>>(x, addin, W_ih, W_hh, b_ih, b_hh,
                                         W1, b1, W2, b2, outp);
}

// Round 11
// 373.614 us; speedup vs baseline: 1.3809x; 1.0794x over previous
//
#include <hip/hip_runtime.h>
#include <cstdint>
#include <cstddef>

#define TSTEPS 512
#define INP    24
#define HID    128
#define BB     4      // batch elems per block; 256 blocks (1/CU)
#define NKT    5      // K = 128 h + 24 x + 8 pad = 160 = 5 tiles of 32
#define VSTR   168    // v[] column stride in fp16 elems: [h 0..127 | x 128..151 | pad]
#define NTHR   576    // 8 compute waves + 1 dedicated staging wave

typedef __attribute__((ext_vector_type(8))) _Float16 half8;   // 8 x fp16 (4 VGPRs)
typedef __attribute__((ext_vector_type(4))) float f32x4;

__device__ __forceinline__ float rcp_f(float v) { return __builtin_amdgcn_rcpf(v); }
__device__ __forceinline__ float sigm_f(float v) {
    return rcp_f(1.0f + __expf(-v));
}
__device__ __forceinline__ float tanh_f(float v) {
    return 1.0f - 2.0f * rcp_f(1.0f + __expf(2.0f * v));
}
__device__ __forceinline__ unsigned pack2h(float a, float b) {
    union { _Float16 h[2]; unsigned u; } z;
    z.h[0] = (_Float16)a; z.h[1] = (_Float16)b;   // v_cvt_f16_f32, RTN
    return z.u;
}
// select a[r] with r = 2*rb1 + rb0; compile-time component indices (R2-safe)
__device__ __forceinline__ float sel4(const f32x4 a, bool rb0, bool rb1) {
    const float lo = rb0 ? a[1] : a[0];
    const float hi = rb0 ? a[3] : a[2];
    return rb1 ? hi : lo;
}

// ROUND LESSONS ENCODED:
//  R1: VGPR-cap betrayal -> scratch spill shows as WRITE_SIZE GBs.
//  R2: runtime-varying index into per-thread arrays demotes to memory.
//  R3: fp32 VALU ~3x too slow; use MFMA.
//  R4/R5: total time == per-block time. MINIMIZE BLOCK WALL (= max over waves).
//  R6: mfma ~19.4 cyc/SIMD. 160 mfma/block/ts invariant -> 776 cyc/SIMD floor.
//  R8: LDS pipe is PER-CU.
//  R9: single-pass fp16 weights/state; absmax ~2^-11.
//  R10: wave-local redistribution, ONE barrier/ts: 619->542us.
//  R11/R12/R13: occupancy attrs spill; HW won't co-schedule 2 blocks/CU.
//  R14: phases SUM within a wave (serial chain).
//  R15: elementwise on 16 lanes = 4x issue tax. Keep 64 lanes.
//  R16: bias->C-init + rcp sigm/tanh + pre-barrier x-tile: 542->453us.
//  R17: exec-masked B-reads regressed. LDS pipe NOT critical path.
//  R18: replica columns (B-read addr clamped to ncol&3 -> 4-way broadcast,
//       cols 4..15 replicas) -> redistribution = 12 cndmask, part_s deleted:
//       453->403us. MfmaUtil 37.5, VALU 34% (640cyc) - wave0 straggler
//       (x-staging) + acc copies identified in residual.
//  R19 (this): UNIFORM WAVE PATHS. (a) 9th wave (block 576) is a dedicated
//      x-stager: compute waves lose the t<48 path, all 8 identical -> no
//      straggler gating the barrier; stage wave has ~1700cyc slack.
//      (b) carried acc feeds kt0 mfma C-in directly (kill 16 v_mov/iter).
//      (c) 4 h-tile ds_reads hoisted to phase top (latency under mfma ramp).
//      Arithmetic identical -> absmax must stay 0.0004882812 exactly.
//      Predict 355-375us, MfmaUtil 40-44, VALUBusy 27-31.
//      Falsifier: <10us move -> structural (mfma+latency) -> setprio or
//      4-wave/BB=8 reshape next.
//
// Per ts: gates[512 x 4] = W[512 x 160] @ v[160 x 4], broadcast to 16 cols.
// mfma_f32_16x16x32_f16:
//   A-frag: lane holds A[m=lane&15][k=quad*8+j]
//   B-frag: lane holds B[k=quad*8+j][n=lane&15]
//   C/D:    col=lane&15, row=quad*4+reg
__global__ __launch_bounds__(NTHR)
void lstm_fused(
    const float* __restrict__ x,      // [B, T, 24]
    const float* __restrict__ addin,  // [B, 2]
    const float* __restrict__ W_ih,   // [512, 24]
    const float* __restrict__ W_hh,   // [512, 128]
    const float* __restrict__ b_ih,   // [512]
    const float* __restrict__ b_hh,   // [512]
    const float* __restrict__ W1,     // [64, 130]
    const float* __restrict__ b1,     // [64]
    const float* __restrict__ W2,     // [3, 64]
    const float* __restrict__ b2,     // [3]
    float* __restrict__ out)          // [B, 3]
{
    __shared__ _Float16 v_s[2][BB * VSTR];   // [buf][col<4][k']; k'<128 h, 128..151 x
    __shared__ float z_s[BB][64];

    const int t    = threadIdx.x;      // 576 threads = 9 waves
    const int lane = t & 63;
    const int wv   = t >> 6;           // 0..8; wave 8 = stager
    const bool is_stage = (wv == 8);
    const int wvc  = is_stage ? 0 : wv;   // clamp for harmless in-bounds setup
    const int ncol = lane & 15;
    const int quad = lane >> 4;
    const int b0   = blockIdx.x * BB;
    const int bsel = ncol & 3;         // broadcast source col = this lane's batch
    const bool rb0 = (ncol >> 2) & 1;  // reg-select bits: r = ncol>>2
    const bool rb1 = (ncol >> 3) & 1;

    // ---- persistent A-fragments (fp16), k' layout: [W_hh | W_ih | 0] ----
    half8 A_w[4][NKT];
    #pragma unroll
    for (int g = 0; g < 4; ++g) {
        const int row = g * HID + wvc * 16 + ncol;
        #pragma unroll
        for (int kt = 0; kt < NKT; ++kt) {
            half8 frag;
            #pragma unroll
            for (int j = 0; j < 8; ++j) {
                const int k = kt * 32 + quad * 8 + j;
                float w = 0.0f;
                if (k < HID)            w = W_hh[row * HID + k];
                else if (k < HID + INP) w = W_ih[row * INP + (k - HID)];
                frag[j] = (_Float16)w;
            }
            A_w[g][kt] = frag;
        }
    }

    // bias as mfma C-init: biasv[g][r] for row quad*4+r (same for all cols)
    f32x4 biasv[4];
    #pragma unroll
    for (int g = 0; g < 4; ++g) {
        #pragma unroll
        for (int r = 0; r < 4; ++r) {
            const int u = wvc * 16 + quad * 4 + r;
            biasv[g][r] = b_ih[g * HID + u] + b_hh[g * HID + u];
        }
    }

    // cell ownership (bijective over 64 lanes x 8 compute waves)
    const int uj = wvc * 16 + quad * 4 + (ncol >> 2);
    float c_reg = 0.0f;

    // staging-wave role: lane sb = lane/12 (batch col), kk (k-pair); 48 active
    const int sb = lane / 12;
    const int kk = lane - sb * 12;
    const size_t xrow = (size_t)(b0 + (sb & 3)) * TSTEPS;

    // ---- init: zero both buffers (B1) ----
    for (int i = t; i < BB * VSTR; i += NTHR) {
        v_s[0][i] = (_Float16)0.0f; v_s[1][i] = (_Float16)0.0f;
    }
    __syncthreads();   // B1

    if (is_stage) {
        // ============ STAGING WAVE ============
        float2 xq = {0.f, 0.f};
        if (lane < 48) {
            const float2 x0 = *(const float2*)(x + (xrow + 0) * INP + kk * 2);
            const float2 x1 = *(const float2*)(x + (xrow + 1) * INP + kk * 2);
            *(unsigned*)&v_s[0][sb * VSTR + HID + kk * 2] = pack2h(x0.x, x0.y);
            *(unsigned*)&v_s[1][sb * VSTR + HID + kk * 2] = pack2h(x1.x, x1.y);
            xq = *(const float2*)(x + (xrow + 2) * INP + kk * 2);
        }
        __syncthreads();   // B2: x(0),x(1) visible for prologue
        __syncthreads();   // B3: prologue consumed buf0 x-region
        for (int ts = 0; ts < TSTEPS; ++ts) {
            const int pb = ts & 1;
            if (lane < 48) {
                const int tsn = (ts + 3 < TSTEPS) ? ts + 3 : TSTEPS - 1;
                const float2 xn = *(const float2*)(x + (xrow + tsn) * INP + kk * 2);
                *(unsigned*)&v_s[pb][sb * VSTR + HID + kk * 2] = pack2h(xq.x, xq.y);
                xq = xn;
            }
            __syncthreads();
        }
    } else {
        // ============ COMPUTE WAVES (uniform, no staging work) ============
        __syncthreads();   // B2

        // prologue pre-step for ts=0: x-tile (kt4) from buf0, C-init = bias
        f32x4 aci, acf, acg, aco;
        {
            const half8 bx = *(const half8*)(&v_s[0][0] + bsel * VSTR + HID + quad * 8);
            aci = __builtin_amdgcn_mfma_f32_16x16x32_f16(A_w[0][4], bx, biasv[0], 0, 0, 0);
            acf = __builtin_amdgcn_mfma_f32_16x16x32_f16(A_w[1][4], bx, biasv[1], 0, 0, 0);
            acg = __builtin_amdgcn_mfma_f32_16x16x32_f16(A_w[2][4], bx, biasv[2], 0, 0, 0);
            aco = __builtin_amdgcn_mfma_f32_16x16x32_f16(A_w[3][4], bx, biasv[3], 0, 0, 0);
        }
        __syncthreads();   // B3

        #pragma unroll 2
        for (int ts = 0; ts < TSTEPS; ++ts) {
            const int pb = ts & 1, nb = pb ^ 1;
            const _Float16* vh = v_s[pb];

            // hoist all B-frag reads to phase top (latency under mfma ramp)
            const half8 bh0 = *(const half8*)(vh + bsel * VSTR + 0 * 32 + quad * 8);
            const half8 bh1 = *(const half8*)(vh + bsel * VSTR + 1 * 32 + quad * 8);
            const half8 bh2 = *(const half8*)(vh + bsel * VSTR + 2 * 32 + quad * 8);
            const half8 bh3 = *(const half8*)(vh + bsel * VSTR + 3 * 32 + quad * 8);
            const half8 bx  = *(const half8*)(&v_s[nb][0] + bsel * VSTR + HID + quad * 8);

            // h-GEMM: carried acc (bias + x-tile) feeds kt0 C-in directly
            f32x4 ai = __builtin_amdgcn_mfma_f32_16x16x32_f16(A_w[0][0], bh0, aci, 0, 0, 0);
            f32x4 af = __builtin_amdgcn_mfma_f32_16x16x32_f16(A_w[1][0], bh0, acf, 0, 0, 0);
            f32x4 ag = __builtin_amdgcn_mfma_f32_16x16x32_f16(A_w[2][0], bh0, acg, 0, 0, 0);
            f32x4 ao = __builtin_amdgcn_mfma_f32_16x16x32_f16(A_w[3][0], bh0, aco, 0, 0, 0);
            ai = __builtin_amdgcn_mfma_f32_16x16x32_f16(A_w[0][1], bh1, ai, 0, 0, 0);
            af = __builtin_amdgcn_mfma_f32_16x16x32_f16(A_w[1][1], bh1, af, 0, 0, 0);
            ag = __builtin_amdgcn_mfma_f32_16x16x32_f16(A_w[2][1], bh1, ag, 0, 0, 0);
            ao = __builtin_amdgcn_mfma_f32_16x16x32_f16(A_w[3][1], bh1, ao, 0, 0, 0);
            ai = __builtin_amdgcn_mfma_f32_16x16x32_f16(A_w[0][2], bh2, ai, 0, 0, 0);
            af = __builtin_amdgcn_mfma_f32_16x16x32_f16(A_w[1][2], bh2, af, 0, 0, 0);
            ag = __builtin_amdgcn_mfma_f32_16x16x32_f16(A_w[2][2], bh2, ag, 0, 0, 0);
            ao = __builtin_amdgcn_mfma_f32_16x16x32_f16(A_w[3][2], bh2, ao, 0, 0, 0);
            ai = __builtin_amdgcn_mfma_f32_16x16x32_f16(A_w[0][3], bh3, ai, 0, 0, 0);
            af = __builtin_amdgcn_mfma_f32_16x16x32_f16(A_w[1][3], bh3, af, 0, 0, 0);
            ag = __builtin_amdgcn_mfma_f32_16x16x32_f16(A_w[2][3], bh3, ag, 0, 0, 0);
            ao = __builtin_amdgcn_mfma_f32_16x16x32_f16(A_w[3][3], bh3, ao, 0, 0, 0);

            // in-register "redistribution": pick this lane's cell (r=ncol>>2)
            const float si = sel4(ai, rb0, rb1);
            const float sf = sel4(af, rb0, rb1);
            const float sg = sel4(ag, rb0, rb1);
            const float so = sel4(ao, rb0, rb1);

            // next-ts x-tile mfma (independent; overlaps trans chain below)
            aci = __builtin_amdgcn_mfma_f32_16x16x32_f16(A_w[0][4], bx, biasv[0], 0, 0, 0);
            acf = __builtin_amdgcn_mfma_f32_16x16x32_f16(A_w[1][4], bx, biasv[1], 0, 0, 0);
            acg = __builtin_amdgcn_mfma_f32_16x16x32_f16(A_w[2][4], bx, biasv[2], 0, 0, 0);
            aco = __builtin_amdgcn_mfma_f32_16x16x32_f16(A_w[3][4], bx, biasv[3], 0, 0, 0);

            // cell update: ALL 64 lanes, one cell each
            {
                const float gi = sigm_f(si);
                const float gf = sigm_f(sf);
                const float gg = tanh_f(sg);
                const float go = sigm_f(so);
                c_reg = gf * c_reg + gi * gg;
                const float h = go * tanh_f(c_reg);
                v_s[nb][bsel * VSTR + uj] = (_Float16)h;
            }

            __syncthreads();
        }
    }

    // ---- FC head: final h is in buffer 0 (ts=511 -> nb=0), offset 0..127 ----
    if (t < 64 * BB) {
        const int b = t >> 6, u = t & 63;
        const float* w = W1 + u * 130;
        float a = b1[u];
        #pragma unroll 16
        for (int k = 0; k < HID; ++k) {
            const float hv = (float)v_s[0][b * VSTR + k];
            a += fmaxf(hv, 0.0f) * w[k];
        }
        const float a0 = addin[(size_t)(b0 + b) * 2 + 0];
        const float a1 = addin[(size_t)(b0 + b) * 2 + 1];
        a += fmaxf(a0, 0.0f) * w[128] + fmaxf(a1, 0.0f) * w[129];
        z_s[b][u] = fmaxf(a, 0.0f);
    }
    __syncthreads();
    if (t < 3 * BB) {
        const int b = t / 3, o = t - 3 * b;
        const float* w = W2 + o * 64;
        float a = b2[o];
        #pragma unroll
        for (int k = 0; k < 64; ++k)
            a += z_s[b][k] * w[k];
        out[(size_t)(b0 + b) * 3 + o] = a;
    }
}

extern "C" void kernel_launch(void* const* d_in, const int* in_sizes, int n_in,
                              void* d_out, int out_size, void* d_ws, size_t ws_size,
                              hipStream_t stream) {
    const float* x     = (const float*)d_in[0];
    const float* addin = (const float*)d_in[1];
    const float* W_ih  = (const float*)d_in[2];
    const float* W_hh  = (const float*)d_in[3];
    const float* b_ih  = (const float*)d_in[4];
    const float* b_hh  = (const float*)d_in[5];
    const float* W1    = (const float*)d_in[6];
    const float* b1    = (const float*)d_in[7];
    const float* W2    = (const float*)d_in[8];
    const float* b2    = (const float*)d_in[9];
    float* outp        = (float*)d_out;

    const int B = in_sizes[0] / (TSTEPS * INP);   // 1024
    const int grid = B / BB;                      // 256 blocks (1 per CU)

    lstm_fused<<<grid, NTHR, 0, stream>>>(x, addin, W_ih, W_hh, b_ih, b_hh,
                                          W1, b1, W2, b2, outp);
}